// Round 5
// baseline (213.804 us; speedup 1.0000x reference)
//
#include <hip/hip_runtime.h>
#include <hip/hip_bf16.h>

// Receiver_46076409152346 — v4.
// Contract: inputs float32, outputs float32.
//
// Collapse identity: pair_left[r,c] = new_state[r>>11, (r>>2)&511] (const per row)
//  => y[bi,rr] = b_y2 + sum_j w_y2[j]*relu(v*ws1[j] + G[rr,j]),
//     v = ns[bi][rr>>2], ws1[j] = sum_{c<512} w_y1[j,c],
//     G[rr,j] = b_y1[j] + sum_c desc[rr,c]*w_y1[j,512+c].
//
// v4: y fused into g's epilogue (G never materialized; 8 j-tile partials
// reduced in softmax). gru/ms/msg/stop restructured to (bi,kg) 512-thread
// blocks with coalesced loads + shfl reduce (v3 had 64-lane stride-2KB
// column reads). ws1+stop merged. 8 dispatches total.

__device__ __forceinline__ float sigm(float x) { return 1.0f / (1.0f + expf(-x)); }

// stage a 512-float row into LDS padded to stride 68 per 64-float group
// (64-stride puts all kg-lanes on one bank; 68 mod 32 = 4 spreads them).
__device__ __forceinline__ void stage_pad68(float* dst, const float* src, int c) {
  *(float4*)&dst[(c >> 4) * 68 + (c & 15) * 4] = *(const float4*)&src[c * 4];
}

// ---------------- K1: GRU. block = h (512), 512 thr: bi=t>>3, kg=t&7.
__global__ __launch_bounds__(512) void gru_kernel(
    const float* __restrict__ msg, const float* __restrict__ st,
    const float* __restrict__ w_ih, const float* __restrict__ w_hh,
    const float* __restrict__ b_ih, const float* __restrict__ b_hh,
    float* __restrict__ ns, float* __restrict__ nsT) {
  const int h = blockIdx.x;
  const int t = threadIdx.x;
  __shared__ __align__(16) float sHr[544], sHz[544], sHn[544];
  __shared__ __align__(16) float sIr[64], sIz[64], sIn[64];
  if (t < 128)      stage_pad68(sHr, w_hh + h * 512, t);
  else if (t < 256) stage_pad68(sHz, w_hh + (h + 512) * 512, t - 128);
  else if (t < 384) stage_pad68(sHn, w_hh + (h + 1024) * 512, t - 256);
  else if (t < 400) ((float4*)sIr)[t - 384] = ((const float4*)(w_ih + h * 64))[t - 384];
  else if (t < 416) ((float4*)sIz)[t - 400] = ((const float4*)(w_ih + (h + 512) * 64))[t - 400];
  else if (t < 432) ((float4*)sIn)[t - 416] = ((const float4*)(w_ih + (h + 1024) * 64))[t - 416];
  __syncthreads();
  const int bi = t >> 3, kg = t & 7;
  float pr = 0.f, pz = 0.f, pin = 0.f, phn = 0.f;
  {  // msg dot: 8 contiguous k per thread
    const float* mrow = msg + bi * 64 + kg * 8;
    const float* ir = &sIr[kg * 8];
    const float* iz = &sIz[kg * 8];
    const float* in_ = &sIn[kg * 8];
    #pragma unroll
    for (int i = 0; i < 2; ++i) {
      float4 x = *(const float4*)&mrow[i * 4];
      float4 wr = *(const float4*)&ir[i * 4];
      float4 wz = *(const float4*)&iz[i * 4];
      float4 wn = *(const float4*)&in_[i * 4];
      pr = fmaf(x.x, wr.x, pr); pr = fmaf(x.y, wr.y, pr); pr = fmaf(x.z, wr.z, pr); pr = fmaf(x.w, wr.w, pr);
      pz = fmaf(x.x, wz.x, pz); pz = fmaf(x.y, wz.y, pz); pz = fmaf(x.z, wz.z, pz); pz = fmaf(x.w, wz.w, pz);
      pin = fmaf(x.x, wn.x, pin); pin = fmaf(x.y, wn.y, pin); pin = fmaf(x.z, wn.z, pin); pin = fmaf(x.w, wn.w, pin);
    }
  }
  {  // state dot: 64 contiguous k per thread
    const float* srow = st + bi * 512 + kg * 64;
    const float* hr = &sHr[kg * 68];
    const float* hz = &sHz[kg * 68];
    const float* hn = &sHn[kg * 68];
    #pragma unroll
    for (int i = 0; i < 16; ++i) {
      float4 x = *(const float4*)&srow[i * 4];
      float4 wr = *(const float4*)&hr[i * 4];
      float4 wz = *(const float4*)&hz[i * 4];
      float4 wn = *(const float4*)&hn[i * 4];
      pr = fmaf(x.x, wr.x, pr); pr = fmaf(x.y, wr.y, pr); pr = fmaf(x.z, wr.z, pr); pr = fmaf(x.w, wr.w, pr);
      pz = fmaf(x.x, wz.x, pz); pz = fmaf(x.y, wz.y, pz); pz = fmaf(x.z, wz.z, pz); pz = fmaf(x.w, wz.w, pz);
      phn = fmaf(x.x, wn.x, phn); phn = fmaf(x.y, wn.y, phn); phn = fmaf(x.z, wn.z, phn); phn = fmaf(x.w, wn.w, phn);
    }
  }
  pr += __shfl_xor(pr, 1, 8); pr += __shfl_xor(pr, 2, 8); pr += __shfl_xor(pr, 4, 8);
  pz += __shfl_xor(pz, 1, 8); pz += __shfl_xor(pz, 2, 8); pz += __shfl_xor(pz, 4, 8);
  pin += __shfl_xor(pin, 1, 8); pin += __shfl_xor(pin, 2, 8); pin += __shfl_xor(pin, 4, 8);
  phn += __shfl_xor(phn, 1, 8); phn += __shfl_xor(phn, 2, 8); phn += __shfl_xor(phn, 4, 8);
  if ((t & 7) == 0) {
    float r = sigm(pr + b_ih[h] + b_hh[h]);
    float z = sigm(pz + b_ih[h + 512] + b_hh[h + 512]);
    float n = tanhf(pin + b_ih[h + 1024] + r * (phn + b_hh[h + 1024]));
    float hp = st[bi * 512 + h];
    float v = (1.0f - z) * n + z * hp;
    ns[bi * 512 + h] = v;
    nsT[h * 64 + bi] = v;
  }
}

// ---------------- K2: ws1 (blocks 0..63, 8 rows each) + stop head (block 64).
__global__ __launch_bounds__(512) void stopws1_kernel(
    const float* __restrict__ w_y1, float* __restrict__ ws1,
    const float* __restrict__ ns, const float* __restrict__ w_stop,
    const float* __restrict__ b_stop, float* __restrict__ out_bit,
    float* __restrict__ out_dist) {
  const int t = threadIdx.x;
  if (blockIdx.x < 64) {
    const int j = blockIdx.x * 8 + (t >> 6);
    const int lane = t & 63;
    const float* row = w_y1 + j * 1024 + lane * 8;
    float4 a = *(const float4*)&row[0];
    float4 b = *(const float4*)&row[4];
    float acc = a.x + a.y + a.z + a.w + b.x + b.y + b.z + b.w;
    #pragma unroll
    for (int m = 1; m < 64; m <<= 1) acc += __shfl_xor(acc, m, 64);
    if (lane == 0) ws1[j] = acc;
  } else {
    const int bi = t >> 3, kg = t & 7;
    const float* row = ns + bi * 512 + kg * 64;
    const float* wrow = w_stop + kg * 64;
    float acc = 0.f;
    #pragma unroll
    for (int i = 0; i < 16; ++i) {
      float4 r = *(const float4*)&row[i * 4];
      float4 w = *(const float4*)&wrow[i * 4];
      acc = fmaf(r.x, w.x, acc); acc = fmaf(r.y, w.y, acc);
      acc = fmaf(r.z, w.z, acc); acc = fmaf(r.w, w.w, acc);
    }
    acc += __shfl_xor(acc, 1, 8); acc += __shfl_xor(acc, 2, 8); acc += __shfl_xor(acc, 4, 8);
    if ((t & 7) == 0) {
      float sd = sigm(acc + b_stop[0]);
      out_dist[bi] = sd;
      out_bit[bi] = rintf(sd);
    }
  }
}

// ---------------- K3: g + fused y epilogue.
// grid (32 rr-tiles, 8 j-tiles) x 256 thr. Computes G tile in regs, then
// y_part[jt][bi][rr] = sum_{j in tile} w_y2[j]*relu(v*ws1[j]+G) via
// 16-lane shfl reduce. G never hits memory.
#define GBK 16
__global__ __launch_bounds__(256) void g_kernel(
    const float* __restrict__ desc, const float* __restrict__ w_y1,
    const float* __restrict__ b_y1, const float* __restrict__ nsT,
    const float* __restrict__ ws1, const float* __restrict__ w_y2,
    float* __restrict__ yp) {
  __shared__ __align__(16) float As[GBK][64];
  __shared__ __align__(16) float Bs[GBK][64];
  __shared__ __align__(16) float sV[16][66];
  __shared__ __align__(16) float sW1[64], sW2[64];
  const int rr0 = blockIdx.x * 64;
  const int j0 = blockIdx.y * 64;
  const int tid = threadIdx.x;
  const int tm = (tid >> 4) * 4;
  const int tn = (tid & 15) * 4;
  const int lm = tid >> 2;
  const int lkq = (tid & 3) * 4;
  {  // epilogue staging (synced by first K-loop barrier)
    const int q = tid >> 4, pos = (tid & 15) * 4;
    *(float4*)&sV[q][pos] = *(const float4*)&nsT[((rr0 >> 2) + q) * 64 + pos];
  }
  if (tid < 64) { sW1[tid] = ws1[j0 + tid]; sW2[tid] = w_y2[j0 + tid]; }
  float acc[4][4] = {};
  const float* aptr = desc + (rr0 + lm) * 512 + lkq;
  const float* bptr = w_y1 + (j0 + lm) * 1024 + 512 + lkq;
  float4 av = *(const float4*)aptr;
  float4 bv = *(const float4*)bptr;
  for (int k0 = 0; k0 < 512; k0 += GBK) {
    __syncthreads();
    As[lkq + 0][lm] = av.x; As[lkq + 1][lm] = av.y;
    As[lkq + 2][lm] = av.z; As[lkq + 3][lm] = av.w;
    Bs[lkq + 0][lm] = bv.x; Bs[lkq + 1][lm] = bv.y;
    Bs[lkq + 2][lm] = bv.z; Bs[lkq + 3][lm] = bv.w;
    __syncthreads();
    if (k0 + GBK < 512) {  // prefetch next tile (hides HBM latency under fma)
      av = *(const float4*)(aptr + k0 + GBK);
      bv = *(const float4*)(bptr + k0 + GBK);
    }
    #pragma unroll
    for (int k = 0; k < GBK; ++k) {
      float4 a = *(const float4*)&As[k][tm];
      float4 b = *(const float4*)&Bs[k][tn];
      acc[0][0] = fmaf(a.x, b.x, acc[0][0]); acc[0][1] = fmaf(a.x, b.y, acc[0][1]);
      acc[0][2] = fmaf(a.x, b.z, acc[0][2]); acc[0][3] = fmaf(a.x, b.w, acc[0][3]);
      acc[1][0] = fmaf(a.y, b.x, acc[1][0]); acc[1][1] = fmaf(a.y, b.y, acc[1][1]);
      acc[1][2] = fmaf(a.y, b.z, acc[1][2]); acc[1][3] = fmaf(a.y, b.w, acc[1][3]);
      acc[2][0] = fmaf(a.z, b.x, acc[2][0]); acc[2][1] = fmaf(a.z, b.y, acc[2][1]);
      acc[2][2] = fmaf(a.z, b.z, acc[2][2]); acc[2][3] = fmaf(a.z, b.w, acc[2][3]);
      acc[3][0] = fmaf(a.w, b.x, acc[3][0]); acc[3][1] = fmaf(a.w, b.y, acc[3][1]);
      acc[3][2] = fmaf(a.w, b.z, acc[3][2]); acc[3][3] = fmaf(a.w, b.w, acc[3][3]);
    }
  }
  // bias
  {
    float4 by = *(const float4*)&b_y1[j0 + tn];
    #pragma unroll
    for (int i = 0; i < 4; ++i) {
      acc[i][0] += by.x; acc[i][1] += by.y; acc[i][2] += by.z; acc[i][3] += by.w;
    }
  }
  // fused y epilogue
  const float4 w1 = *(const float4*)&sW1[tn];
  const float4 w2 = *(const float4*)&sW2[tn];
  const int vrow = tid >> 4;
  float* ypb = yp + blockIdx.y * 131072 + rr0 + tm;
  for (int bi = 0; bi < 64; ++bi) {
    const float v = sV[vrow][bi];
    float p0 = fmaf(w2.x, fmaxf(fmaf(v, w1.x, acc[0][0]), 0.f),
               fmaf(w2.y, fmaxf(fmaf(v, w1.y, acc[0][1]), 0.f),
               fmaf(w2.z, fmaxf(fmaf(v, w1.z, acc[0][2]), 0.f),
                    w2.w * fmaxf(fmaf(v, w1.w, acc[0][3]), 0.f))));
    float p1 = fmaf(w2.x, fmaxf(fmaf(v, w1.x, acc[1][0]), 0.f),
               fmaf(w2.y, fmaxf(fmaf(v, w1.y, acc[1][1]), 0.f),
               fmaf(w2.z, fmaxf(fmaf(v, w1.z, acc[1][2]), 0.f),
                    w2.w * fmaxf(fmaf(v, w1.w, acc[1][3]), 0.f))));
    float p2 = fmaf(w2.x, fmaxf(fmaf(v, w1.x, acc[2][0]), 0.f),
               fmaf(w2.y, fmaxf(fmaf(v, w1.y, acc[2][1]), 0.f),
               fmaf(w2.z, fmaxf(fmaf(v, w1.z, acc[2][2]), 0.f),
                    w2.w * fmaxf(fmaf(v, w1.w, acc[2][3]), 0.f))));
    float p3 = fmaf(w2.x, fmaxf(fmaf(v, w1.x, acc[3][0]), 0.f),
               fmaf(w2.y, fmaxf(fmaf(v, w1.y, acc[3][1]), 0.f),
               fmaf(w2.z, fmaxf(fmaf(v, w1.z, acc[3][2]), 0.f),
                    w2.w * fmaxf(fmaf(v, w1.w, acc[3][3]), 0.f))));
    p0 += __shfl_xor(p0, 1, 16); p0 += __shfl_xor(p0, 2, 16); p0 += __shfl_xor(p0, 4, 16); p0 += __shfl_xor(p0, 8, 16);
    p1 += __shfl_xor(p1, 1, 16); p1 += __shfl_xor(p1, 2, 16); p1 += __shfl_xor(p1, 4, 16); p1 += __shfl_xor(p1, 8, 16);
    p2 += __shfl_xor(p2, 1, 16); p2 += __shfl_xor(p2, 2, 16); p2 += __shfl_xor(p2, 4, 16); p2 += __shfl_xor(p2, 8, 16);
    p3 += __shfl_xor(p3, 1, 16); p3 += __shfl_xor(p3, 2, 16); p3 += __shfl_xor(p3, 4, 16); p3 += __shfl_xor(p3, 8, 16);
    if ((tid & 15) == 0) *(float4*)&ypb[bi * 2048] = make_float4(p0, p1, p2, p3);
  }
}

// ---------------- K4: softmax (sums 8 y-partials + b_y2). block = bi, 256 thr.
__global__ __launch_bounds__(256) void softmax_kernel(
    const float* __restrict__ yp, const float* __restrict__ b_y2,
    float* __restrict__ scores, float* __restrict__ out_y) {
  const int bi = blockIdx.x;
  const int t = threadIdx.x;
  __shared__ float sy[2048];
  __shared__ float red[256];
  const float b = b_y2[0];
  float lmax = -3.0e38f;
  for (int i = t; i < 2048; i += 256) {
    const float* p = yp + bi * 2048 + i;
    float v = b + p[0] + p[131072] + p[262144] + p[393216]
                + p[524288] + p[655360] + p[786432] + p[917504];
    sy[i] = v;
    out_y[bi * 2048 + i] = v;
    lmax = fmaxf(lmax, v);
  }
  red[t] = lmax;
  __syncthreads();
  for (int s = 128; s > 0; s >>= 1) {
    if (t < s) red[t] = fmaxf(red[t], red[t + s]);
    __syncthreads();
  }
  const float mx = red[0];
  __syncthreads();
  float lsum = 0.0f;
  for (int i = t; i < 2048; i += 256) {
    float e = expf(sy[i] - mx);
    sy[i] = e;
    lsum += e;
  }
  red[t] = lsum;
  __syncthreads();
  for (int s = 128; s > 0; s >>= 1) {
    if (t < s) red[t] += red[t + s];
    __syncthreads();
  }
  const float inv = 1.0f / red[0];
  for (int i = t; i < 2048; i += 256) scores[bi * 2048 + i] = sy[i] * inv;
}

// ---------------- K5: di partials. grid (8 d-tiles, 32 n-chunks) x 256.
__global__ __launch_bounds__(256) void di_part_kernel(
    const float* __restrict__ scores, const float* __restrict__ desc,
    float* __restrict__ dp) {
  __shared__ __align__(16) float sS[64][64];
  __shared__ __align__(16) float sD[64][64];
  const int d0 = blockIdx.x * 64;
  const int n0 = blockIdx.y * 64;
  const int tid = threadIdx.x;
  {
    const int bi = tid >> 2;
    #pragma unroll
    for (int i = 0; i < 4; ++i) {
      const int kq = (tid & 3) * 4 + i * 16;
      float4 av = *(const float4*)&scores[bi * 2048 + n0 + kq];
      sS[kq + 0][bi] = av.x; sS[kq + 1][bi] = av.y;
      sS[kq + 2][bi] = av.z; sS[kq + 3][bi] = av.w;
    }
  }
  {
    #pragma unroll
    for (int i = 0; i < 4; ++i) {
      const int nn = (tid >> 4) + i * 16;
      const int dq = (tid & 15) * 4;
      *(float4*)&sD[nn][dq] = *(const float4*)&desc[(n0 + nn) * 512 + d0 + dq];
    }
  }
  __syncthreads();
  const int bi0 = (tid >> 4) * 4;
  const int dd0 = (tid & 15) * 4;
  float acc[4][4] = {};
  #pragma unroll 8
  for (int nn = 0; nn < 64; ++nn) {
    float4 a = *(const float4*)&sS[nn][bi0];
    float4 b = *(const float4*)&sD[nn][dd0];
    acc[0][0] = fmaf(a.x, b.x, acc[0][0]); acc[0][1] = fmaf(a.x, b.y, acc[0][1]);
    acc[0][2] = fmaf(a.x, b.z, acc[0][2]); acc[0][3] = fmaf(a.x, b.w, acc[0][3]);
    acc[1][0] = fmaf(a.y, b.x, acc[1][0]); acc[1][1] = fmaf(a.y, b.y, acc[1][1]);
    acc[1][2] = fmaf(a.y, b.z, acc[1][2]); acc[1][3] = fmaf(a.y, b.w, acc[1][3]);
    acc[2][0] = fmaf(a.z, b.x, acc[2][0]); acc[2][1] = fmaf(a.z, b.y, acc[2][1]);
    acc[2][2] = fmaf(a.z, b.z, acc[2][2]); acc[2][3] = fmaf(a.z, b.w, acc[2][3]);
    acc[3][0] = fmaf(a.w, b.x, acc[3][0]); acc[3][1] = fmaf(a.w, b.y, acc[3][1]);
    acc[3][2] = fmaf(a.w, b.z, acc[3][2]); acc[3][3] = fmaf(a.w, b.w, acc[3][3]);
  }
  float* base = dp + blockIdx.y * 32768;
  #pragma unroll
  for (int i = 0; i < 4; ++i)
    #pragma unroll
    for (int j = 0; j < 4; ++j)
      base[(bi0 + i) * 512 + d0 + dd0 + j] = acc[i][j];
}

// ---------------- K6: reduce 32 di partials. 64 blocks x 512.
__global__ __launch_bounds__(512) void di_reduce_kernel(
    const float* __restrict__ dp, float* __restrict__ di) {
  const int idx = blockIdx.x * 512 + threadIdx.x;
  float acc = 0.0f;
  #pragma unroll 8
  for (int c = 0; c < 32; ++c) acc += dp[c * 32768 + idx];
  di[idx] = acc;
}

// ---------------- K7: message_state. block = hj (512), 512 thr (bi,kg).
__global__ __launch_bounds__(512) void ms_kernel(
    const float* __restrict__ ns, const float* __restrict__ di,
    const float* __restrict__ w_state, const float* __restrict__ b_state,
    const float* __restrict__ w_desc, float* __restrict__ ms) {
  const int hj = blockIdx.x;
  const int t = threadIdx.x;
  __shared__ __align__(16) float sWs[544], sWd[544];
  if (t < 128)      stage_pad68(sWs, w_state + hj * 512, t);
  else if (t < 256) stage_pad68(sWd, w_desc + hj * 512, t - 128);
  __syncthreads();
  const int bi = t >> 3, kg = t & 7;
  const float* nr = ns + bi * 512 + kg * 64;
  const float* dr = di + bi * 512 + kg * 64;
  const float* wsp = &sWs[kg * 68];
  const float* wdp = &sWd[kg * 68];
  float acc = 0.f;
  #pragma unroll
  for (int i = 0; i < 16; ++i) {
    float4 a = *(const float4*)&nr[i * 4];
    float4 w = *(const float4*)&wsp[i * 4];
    float4 b = *(const float4*)&dr[i * 4];
    float4 u = *(const float4*)&wdp[i * 4];
    acc = fmaf(a.x, w.x, acc); acc = fmaf(a.y, w.y, acc);
    acc = fmaf(a.z, w.z, acc); acc = fmaf(a.w, w.w, acc);
    acc = fmaf(b.x, u.x, acc); acc = fmaf(b.y, u.y, acc);
    acc = fmaf(b.z, u.z, acc); acc = fmaf(b.w, u.w, acc);
  }
  acc += __shfl_xor(acc, 1, 8); acc += __shfl_xor(acc, 2, 8); acc += __shfl_xor(acc, 4, 8);
  if ((t & 7) == 0) ms[bi * 512 + hj] = tanhf(acc + b_state[hj]);
}

// ---------------- K8: message head. block = m (64), 512 thr (bi,kg).
__global__ __launch_bounds__(512) void msg_kernel(
    const float* __restrict__ ms, const float* __restrict__ w_msg,
    const float* __restrict__ b_msg, float* __restrict__ out_msg,
    float* __restrict__ out_msgdist) {
  const int m = blockIdx.x;
  const int t = threadIdx.x;
  __shared__ __align__(16) float sW[544];
  if (t < 128) stage_pad68(sW, w_msg + m * 512, t);
  __syncthreads();
  const int bi = t >> 3, kg = t & 7;
  const float* row = ms + bi * 512 + kg * 64;
  const float* wp = &sW[kg * 68];
  float acc = 0.f;
  #pragma unroll
  for (int i = 0; i < 16; ++i) {
    float4 a = *(const float4*)&row[i * 4];
    float4 w = *(const float4*)&wp[i * 4];
    acc = fmaf(a.x, w.x, acc); acc = fmaf(a.y, w.y, acc);
    acc = fmaf(a.z, w.z, acc); acc = fmaf(a.w, w.w, acc);
  }
  acc += __shfl_xor(acc, 1, 8); acc += __shfl_xor(acc, 2, 8); acc += __shfl_xor(acc, 4, 8);
  if ((t & 7) == 0) {
    float md = sigm(acc + b_msg[m]);
    out_msgdist[bi * 64 + m] = md;
    out_msg[bi * 64 + m] = rintf(md);
  }
}

extern "C" void kernel_launch(void* const* d_in, const int* in_sizes, int n_in,
                              void* d_out, int out_size, void* d_ws, size_t ws_size,
                              hipStream_t stream) {
  (void)in_sizes; (void)n_in; (void)out_size; (void)ws_size;
  const float* message = (const float*)d_in[0];
  const float* state   = (const float*)d_in[1];
  const float* desc    = (const float*)d_in[3];
  const float* w_ih    = (const float*)d_in[4];
  const float* w_hh    = (const float*)d_in[5];
  const float* b_ih    = (const float*)d_in[6];
  const float* b_hh    = (const float*)d_in[7];
  const float* w_stop  = (const float*)d_in[8];
  const float* b_stop  = (const float*)d_in[9];
  const float* w_y1    = (const float*)d_in[10];
  const float* b_y1    = (const float*)d_in[11];
  const float* w_y2    = (const float*)d_in[12];
  const float* b_y2    = (const float*)d_in[13];
  const float* w_state = (const float*)d_in[14];
  const float* b_state = (const float*)d_in[15];
  const float* w_desc  = (const float*)d_in[16];
  const float* w_msg   = (const float*)d_in[17];
  const float* b_msg   = (const float*)d_in[18];

  float* out = (float*)d_out;
  float* out_stopbit  = out;          // [64]
  float* out_stopdist = out + 64;     // [64]
  float* out_msg      = out + 128;    // [64*64]
  float* out_msgdist  = out + 4224;   // [64*64]
  float* out_y        = out + 8320;   // [64*2048]

  char* ws = (char*)d_ws;
  float* ns     = (float*)(ws);             // 64*512
  float* nsT    = (float*)(ws + 131072);    // 512*64
  float* ws1    = (float*)(ws + 262144);    // 512
  float* yp     = (float*)(ws + 270336);    // 8*64*2048 (reused as di partials)
  float* scores = (float*)(ws + 4988928);   // 64*2048
  float* di     = (float*)(ws + 5513216);   // 64*512
  float* ms     = (float*)(ws + 5644288);   // 64*512

  gru_kernel<<<512, 512, 0, stream>>>(message, state, w_ih, w_hh, b_ih, b_hh, ns, nsT);
  stopws1_kernel<<<65, 512, 0, stream>>>(w_y1, ws1, ns, w_stop, b_stop, out_stopbit, out_stopdist);
  g_kernel<<<dim3(32, 8), 256, 0, stream>>>(desc, w_y1, b_y1, nsT, ws1, w_y2, yp);
  softmax_kernel<<<64, 256, 0, stream>>>(yp, b_y2, scores, out_y);
  di_part_kernel<<<dim3(8, 32), 256, 0, stream>>>(scores, desc, yp);  // yp dead -> dp
  di_reduce_kernel<<<64, 512, 0, stream>>>(yp, di);
  ms_kernel<<<512, 512, 0, stream>>>(ns, di, w_state, b_state, w_desc, ms);
  msg_kernel<<<64, 512, 0, stream>>>(ms, w_msg, b_msg, out_msg, out_msgdist);
}